// Round 7
// baseline (326.645 us; speedup 1.0000x reference)
//
#include <hip/hip_runtime.h>

// Problem constants (fixed by setup_inputs)
static constexpr int V  = 5;
static constexpr int B  = 2;
static constexpr int C  = 32;
static constexpr int H  = 256;
static constexpr int W  = 320;
static constexpr int CN = 4;
static constexpr int HW = H * W;
static constexpr int CG = 8;   // channels per group (per wave)
static constexpr int NG = 4;   // groups per block
static constexpr int XT = W / 64;        // 5 x-tiles
static constexpr int NBLK = XT * H * B;  // 2560 fused blocks

static constexpr size_t PARAMS_OFF = 0;

typedef float f32x2 __attribute__((ext_vector_type(2)));
typedef float f32x4 __attribute__((ext_vector_type(4)));

// Alignment-safe paired load (global: dwordx2; LDS: ds_read2_b32 / b64)
__device__ __forceinline__ f32x2 ld2(const float* p) {
    f32x2 v;
    __builtin_memcpy(&v, p, sizeof(f32x2));
    return v;
}

// ---------------------------------------------------------------------------
// Setup: per (b, src view i=1..4) compute proj = M_i @ inv(M_0) -> 12 floats
// ---------------------------------------------------------------------------
__global__ void setup_proj_kernel(const float* __restrict__ pm, float* __restrict__ params) {
    int b = threadIdx.x;
    if (b >= B) return;

    float M[V][16];
    for (int v = 0; v < V; ++v) {
        const float* E  = pm + ((size_t)(b * V + v) * 2 + 0) * 16;
        const float* Km = pm + ((size_t)(b * V + v) * 2 + 1) * 16;
        for (int r = 0; r < 3; ++r)
            for (int c = 0; c < 4; ++c) {
                float s = 0.f;
                for (int k = 0; k < 3; ++k) s += Km[r * 4 + k] * E[k * 4 + c];
                M[v][r * 4 + c] = s;
            }
        for (int c = 0; c < 4; ++c) M[v][12 + c] = E[12 + c];
    }

    float A[9], bb[3];
    for (int r = 0; r < 3; ++r) {
        for (int c = 0; c < 3; ++c) A[r * 3 + c] = M[0][r * 4 + c];
        bb[r] = M[0][r * 4 + 3];
    }
    float det = A[0] * (A[4] * A[8] - A[5] * A[7])
              - A[1] * (A[3] * A[8] - A[5] * A[6])
              + A[2] * (A[3] * A[7] - A[4] * A[6]);
    float id = 1.f / det;
    float Ai[9];
    Ai[0] = (A[4] * A[8] - A[5] * A[7]) * id;
    Ai[1] = (A[2] * A[7] - A[1] * A[8]) * id;
    Ai[2] = (A[1] * A[5] - A[2] * A[4]) * id;
    Ai[3] = (A[5] * A[6] - A[3] * A[8]) * id;
    Ai[4] = (A[0] * A[8] - A[2] * A[6]) * id;
    Ai[5] = (A[2] * A[3] - A[0] * A[5]) * id;
    Ai[6] = (A[3] * A[7] - A[4] * A[6]) * id;
    Ai[7] = (A[1] * A[6] - A[0] * A[7]) * id;
    Ai[8] = (A[0] * A[4] - A[1] * A[3]) * id;
    float bi[3];
    for (int r = 0; r < 3; ++r)
        bi[r] = -(Ai[r * 3 + 0] * bb[0] + Ai[r * 3 + 1] * bb[1] + Ai[r * 3 + 2] * bb[2]);

    float Minv[16];
    for (int r = 0; r < 3; ++r) {
        for (int c = 0; c < 3; ++c) Minv[r * 4 + c] = Ai[r * 3 + c];
        Minv[r * 4 + 3] = bi[r];
    }
    Minv[12] = 0.f; Minv[13] = 0.f; Minv[14] = 0.f; Minv[15] = 1.f;

    for (int v = 1; v < V; ++v) {
        float* dst = params + (size_t)(b * (V - 1) + (v - 1)) * 12;
        for (int r = 0; r < 3; ++r)
            for (int c = 0; c < 4; ++c) {
                float s = 0.f;
                for (int k = 0; k < 4; ++k) s += M[v][r * 4 + k] * Minv[k * 4 + c];
                dst[r * 4 + c] = s;
            }
    }
}

// ---------------------------------------------------------------------------
// Fused kernel v7 = r5 (142.6us, VGPR 64) minus its serialization:
//  (1) NO barriers in the view/phase loops: stage[g] is wave-private
//      (written and read only by wave g); same-wave DS ops execute in order,
//      so WAR on the stage buffer across phases is hardware-safe.
//  (2) paired gather reads: (o0,o0+1) and (o0+320,o0+321) as f32x2 ->
//      ds_read2-class, halving gather LDS instruction count.
//  (3) issue-early staging (T14): the next phase's 8 global dwordx4 loads are
//      issued right after the current phase's ds_writes, hiding HBM/L2
//      latency under the gather+FMA. One R[8] register set; LDS (31KB ->
//      5 blocks/CU) caps occupancy at VGPR~102 so the +32 VGPR is free.
// Staging via regs+ds_write (NOT global_load_lds: r6 showed the DMA path
// costs ~56 extra VGPR in this kernel and halves occupancy).
// ---------------------------------------------------------------------------
__global__ __launch_bounds__(256) void fused_kernel(
    const float* __restrict__ depth_values,   // (B,1,H,W)
    const float* __restrict__ features,       // (V,B,C,H,W)
    const float* __restrict__ depth_interval, // (B,1,H,W)
    const float* __restrict__ view_weights,   // (B,V-1,H,W)
    const float* __restrict__ params,         // (B,V-1,12)
    float* __restrict__ out)                  // (B,C*CN,H,W)
{
    const int tid = threadIdx.x;
    const int p   = tid & 63;
    const int g   = tid >> 6;

    // row-sharing XCD swizzle (bijective): class d&7 -> XCD residue,
    // within class sweep x-tiles then a contiguous 64-row slab.
    const int d   = blockIdx.x;
    const int u   = d >> 3;             // 0..319
    const int r8  = d & 7;
    const int xt  = u % XT;
    const int rid = r8 * 64 + u / XT;   // 0..511
    const int y   = rid & (H - 1);
    const int b   = rid >> 8;

    const int x   = xt * 64 + p;
    const int pix = y * W + x;

    __shared__ float sp4[48];            // 4 views x 12 params
    __shared__ float stage[NG][1920];    // per-group: 2ch x 3 rows x 320 (30.7 KB)
    float* const sredp = &stage[0][0];   // aliased post-gather: [NG][CN][64]
    float* const simp  = &stage[0][1024];// aliased post-gather: [CN][64]

    if (tid < 48) sp4[tid] = params[(size_t)b * 48 + tid];
    __syncthreads();

    const float invd = 1.f / depth_values[(size_t)b * HW + pix];
    const float itv  = depth_interval[(size_t)b * HW + pix];
    const float low  = invd - (CN * 0.5f) * itv;
    const float step = (CN * itv) / (float)(CN - 1);
    float dep[CN];
#pragma unroll
    for (int k = 0; k < CN; ++k) dep[k] = 1.f / (low + (float)k * step);

    // prefetch all 4 view weights (off the per-view critical chain)
    float vws[V - 1];
#pragma unroll
    for (int i = 0; i < V - 1; ++i)
        vws[i] = view_weights[((size_t)b * (V - 1) + i) * HW + pix];
    float wsum = 1e-5f;
#pragma unroll
    for (int i = 0; i < V - 1; ++i) wsum += vws[i];

    // this group's reference channels: read once -> NT load
    const float* refp = features + ((size_t)b * C + g * CG) * HW + pix;
    float rf[CG];
#pragma unroll
    for (int c = 0; c < CG; ++c) rf[c] = __builtin_nontemporal_load(refp + (size_t)c * HW);

    // per-lane staging source offsets (phase-independent). Slot = it*64+p
    // covers 480 f32x4 = 1920 floats = 2 ch x 3 rows x 320. chl folded in.
    // Valid slots: slot < 480  <=>  it<7 || p<32.
    int soff[8];
#pragma unroll
    for (int it = 0; it < 8; ++it) {
        const int slot = it * 64 + p;
        const int f    = slot * 4;
        const int chl  = (f >= 960) ? 1 : 0;
        const int rem  = f - chl * 960;
        const int j    = rem / 320;
        const int col  = rem - j * 320;
        const int row  = min(max(y - 1 + j, 0), H - 1);
        soff[it] = chl * HW + row * W + col;
    }

    const float* srcgv[V - 1];
#pragma unroll
    for (int i = 0; i < V - 1; ++i)
        srcgv[i] = features + ((size_t)((i + 1) * B + b) * C + g * CG) * HW;

    const float fx = (float)x, fy = (float)y;
    float volsum[CN] = {0.f, 0.f, 0.f, 0.f};

    // staging register set; loaded for (view iv, phase ph) one phase early
    f32x4 R[8];
#pragma unroll
    for (int it = 0; it < 8; ++it)
        if (it < 7 || p < 32) R[it] = *(const f32x4*)(srcgv[0] + soff[it]);

    for (int iv = 0; iv < V - 1; ++iv) {
        const float* spv = &sp4[iv * 12];
        const float rx = spv[0] * fx + spv[1] * fy + spv[2];
        const float ry = spv[4] * fx + spv[5] * fy + spv[6];
        const float rz = spv[8] * fx + spv[9] * fy + spv[10];
        const float tx = spv[3], ty = spv[7], tz = spv[11];

        const float scale = vws[iv] * (1.f / (float)C);

        int   bx_[CN], y0_[CN];
        float wA0[CN], wB0[CN], wA1[CN], wB1[CN];
#pragma unroll
        for (int k = 0; k < CN; ++k) {
            const float dd = dep[k];
            const float px = rx * dd + tx;
            const float py = ry * dd + ty;
            const float pz = rz * dd + tz;
            const float iz = 1.f / pz;
            const float gx = px * iz;
            const float gy = py * iz;

            const float x0f = floorf(gx), y0f = floorf(gy);
            const float wx1 = gx - x0f, wy1 = gy - y0f;
            const float wx0 = 1.f - wx1, wy0 = 1.f - wy1;
            const int x0 = (int)x0f, y0 = (int)y0f;
            const int x1 = x0 + 1, y1 = y0 + 1;

            const bool vx0 = (x0 >= 0) && (x0 <= W - 1);
            const bool vx1 = (x1 >= 0) && (x1 <= W - 1);
            const bool vy0 = (y0 >= 0) && (y0 <= H - 1);
            const bool vy1 = (y1 >= 0) && (y1 <= H - 1);

            const int bx = min(max(x0, 0), W - 2);
            const int s  = x0 - bx;   // {-1, 0, 1} (else all weights 0)

            const float w00 = wx0 * wy0 * ((vx0 && vy0) ? scale : 0.f);
            const float w10 = wx1 * wy0 * ((vx1 && vy0) ? scale : 0.f);
            const float w01 = wx0 * wy1 * ((vx0 && vy1) ? scale : 0.f);
            const float w11 = wx1 * wy1 * ((vx1 && vy1) ? scale : 0.f);

            wA0[k] = (s == 0) ? w00 : ((s == -1) ? w10 : 0.f);
            wB0[k] = (s == 0) ? w10 : ((s == 1) ? w00 : 0.f);
            wA1[k] = (s == 0) ? w01 : ((s == -1) ? w11 : 0.f);
            wB1[k] = (s == 0) ? w11 : ((s == 1) ? w01 : 0.f);

            bx_[k] = bx;
            y0_[k] = y0;
        }

        // fast iff every lane's floor row is y-1 or y (staged rows cover it,
        // incl. image-edge clamping). Per-WAVE verdict; no barriers anywhere.
        bool okrow = true;
#pragma unroll
        for (int k = 0; k < CN; ++k)
            okrow = okrow && (y0_[k] >= y - 1) && (y0_[k] <= y);

        if (__all(okrow)) {
            int o0[CN];
#pragma unroll
            for (int k = 0; k < CN; ++k)
                o0[k] = (y0_[k] - y + 1) * 320 + bx_[k];

#pragma unroll
            for (int ph = 0; ph < 4; ++ph) {
                // commit staged regs for this phase (same-wave in-order DS:
                // previous phase's reads retire before these writes land)
#pragma unroll
                for (int it = 0; it < 8; ++it)
                    if (it < 7 || p < 32)
                        *(f32x4*)&stage[g][(it * 64 + p) * 4] = R[it];

                // issue-early: next phase's global loads fly under the gather
                if (ph < 3) {
                    const float* nsrc = srcgv[iv] + (size_t)(2 * (ph + 1)) * HW;
#pragma unroll
                    for (int it = 0; it < 8; ++it)
                        if (it < 7 || p < 32) R[it] = *(const f32x4*)(nsrc + soff[it]);
                } else if (iv < V - 2) {
                    const float* nsrc = srcgv[iv + 1];
#pragma unroll
                    for (int it = 0; it < 8; ++it)
                        if (it < 7 || p < 32) R[it] = *(const f32x4*)(nsrc + soff[it]);
                }

                // gather this phase's 2 channels x 4 depths (paired reads)
#pragma unroll
                for (int c2 = 0; c2 < 2; ++c2) {
                    const float rfc = rf[2 * ph + c2];
                    const float* L = &stage[g][c2 * 960];
#pragma unroll
                    for (int k = 0; k < CN; ++k) {
                        const f32x2 a  = ld2(L + o0[k]);
                        const f32x2 b2 = ld2(L + o0[k] + 320);
                        float t = wA0[k] * a.x;
                        t = fmaf(wB0[k], a.y, t);
                        t = fmaf(wA1[k], b2.x, t);
                        t = fmaf(wB1[k], b2.y, t);
                        volsum[k] = fmaf(rfc, t, volsum[k]);
                    }
                }
            }
        } else {
            // GENERIC fallback (cold): compact global gather, minimal registers.
            int ib0[CN], ib1[CN];
#pragma unroll
            for (int k = 0; k < CN; ++k) {
                const int cy0 = min(max(y0_[k],     0), H - 1);
                const int cy1 = min(max(y0_[k] + 1, 0), H - 1);
                ib0[k] = cy0 * W + bx_[k];
                ib1[k] = cy1 * W + bx_[k];
            }
            const float* srcg = srcgv[iv];
#pragma unroll 1
            for (int c = 0; c < CG; ++c) {
                const float* fc  = srcg + (size_t)c * HW;
                const float  rfc = rf[c];
#pragma unroll 1
                for (int k = 0; k < CN; ++k) {
                    const f32x2 a   = ld2(fc + ib0[k]);
                    const f32x2 bb2 = ld2(fc + ib1[k]);
                    float t = wA0[k] * a.x;
                    t = fmaf(wB0[k], a.y, t);
                    t = fmaf(wA1[k], bb2.x, t);
                    t = fmaf(wB1[k], bb2.y, t);
                    volsum[k] = fmaf(rfc, t, volsum[k]);
                }
            }
            // re-prime the staging pipeline for the next view
            if (iv < V - 2) {
#pragma unroll
                for (int it = 0; it < 8; ++it)
                    if (it < 7 || p < 32) R[it] = *(const f32x4*)(srcgv[iv + 1] + soff[it]);
            }
        }
    }

    // cross-group reduce + normalize; sred/sim alias the (now dead) stage buf.
    __syncthreads();
#pragma unroll
    for (int k = 0; k < CN; ++k) sredp[(g * CN + k) * 64 + p] = volsum[k];
    __syncthreads();

    {
        const int k = g;   // NG == CN: group g owns depth k = g
        const float s = sredp[(0 * CN + k) * 64 + p] + sredp[(1 * CN + k) * 64 + p]
                      + sredp[(2 * CN + k) * 64 + p] + sredp[(3 * CN + k) * 64 + p];
        simp[k * 64 + p] = s * (1.f / wsum);
    }
    __syncthreads();

    // broadcast-write 128 planes x 64 px with regular cached stores.
    {
        const int quad = tid & 15;
        const int pc   = tid >> 4;
        float* op = out + (size_t)b * C * CN * HW + y * W + xt * 64 + quad * 4;
#pragma unroll
        for (int j = 0; j < 8; ++j) {
            const int plane = pc * 8 + j;          // 0..127, each exactly once
            const int k     = plane & 3;
            const f32x4 v   = *(const f32x4*)&simp[k * 64 + quad * 4];
            *(f32x4*)(op + (size_t)plane * HW) = v;
        }
    }
}

extern "C" void kernel_launch(void* const* d_in, const int* in_sizes, int n_in,
                              void* d_out, int out_size, void* d_ws, size_t ws_size,
                              hipStream_t stream) {
    const float* depth_values   = (const float*)d_in[0];
    const float* features       = (const float*)d_in[1];
    const float* proj_matrices  = (const float*)d_in[2];
    const float* depth_interval = (const float*)d_in[3];
    const float* view_weights   = (const float*)d_in[7];
    float* out    = (float*)d_out;
    float* params = (float*)d_ws + PARAMS_OFF;    // 96 floats

    setup_proj_kernel<<<1, B, 0, stream>>>(proj_matrices, params);

    fused_kernel<<<NBLK, 256, 0, stream>>>(depth_values, features, depth_interval,
                                           view_weights, params, out);
}